// Round 1
// baseline (456.511 us; speedup 1.0000x reference)
//
#include <hip/hip_runtime.h>
#include <hip/hip_bf16.h>
#include <math.h>

// Problem constants (from reference)
#define N_NODES 50000
#define N_EDGES 800000
#define E_TOT   (N_EDGES + N_NODES)   // edges + self loops = 850000
#define HID     128
#define N_GRAPHS 64
#define NEG_SLOPE 0.2f

#define SCAN_B 256
#define NB_SCAN ((N_NODES + SCAN_B - 1) / SCAN_B)   // 196

// ---------------------------------------------------------------------------
// CSR build: count degrees -> 2-level exclusive scan -> scatter edge sources
// ---------------------------------------------------------------------------
__global__ void count_deg(const int* __restrict__ edge_dst, int* __restrict__ deg) {
    int e = blockIdx.x * blockDim.x + threadIdx.x;
    if (e >= E_TOT) return;
    int dst = (e < N_EDGES) ? edge_dst[e] : (e - N_EDGES);
    atomicAdd(&deg[dst], 1);
}

__global__ void scan1(const int* __restrict__ deg, int* __restrict__ row_start,
                      int* __restrict__ bsums) {
    __shared__ int s[SCAN_B];
    int tid = threadIdx.x;
    int i = blockIdx.x * SCAN_B + tid;
    int v = (i < N_NODES) ? deg[i] : 0;
    s[tid] = v;
    __syncthreads();
    for (int off = 1; off < SCAN_B; off <<= 1) {
        int t = (tid >= off) ? s[tid - off] : 0;
        __syncthreads();
        s[tid] += t;
        __syncthreads();
    }
    if (i < N_NODES) row_start[i] = s[tid] - v;   // exclusive, no block offset yet
    if (tid == SCAN_B - 1) bsums[blockIdx.x] = s[tid];
}

__global__ void scan2(const int* __restrict__ bsums, int* __restrict__ boff,
                      int* __restrict__ row_start) {
    __shared__ int s[SCAN_B];
    int tid = threadIdx.x;
    int v = (tid < NB_SCAN) ? bsums[tid] : 0;
    s[tid] = v;
    __syncthreads();
    for (int off = 1; off < SCAN_B; off <<= 1) {
        int t = (tid >= off) ? s[tid - off] : 0;
        __syncthreads();
        s[tid] += t;
        __syncthreads();
    }
    if (tid < NB_SCAN) boff[tid] = s[tid] - v;
    if (tid == SCAN_B - 1) row_start[N_NODES] = s[tid];   // total = E_TOT
}

__global__ void scan3(int* __restrict__ row_start, const int* __restrict__ boff,
                      int* __restrict__ cursor) {
    int i = blockIdx.x * SCAN_B + threadIdx.x;
    if (i >= N_NODES) return;
    int r = row_start[i] + boff[blockIdx.x];
    row_start[i] = r;
    cursor[i] = r;
}

__global__ void fill_csr(const int* __restrict__ edge_src, const int* __restrict__ edge_dst,
                         int* __restrict__ cursor, int* __restrict__ csr_src) {
    int e = blockIdx.x * blockDim.x + threadIdx.x;
    if (e >= E_TOT) return;
    int s, d;
    if (e < N_EDGES) { s = edge_src[e]; d = edge_dst[e]; }
    else             { s = d = e - N_EDGES; }
    int pos = atomicAdd(&cursor[d], 1);
    csr_src[pos] = s;
}

// Graph boundaries from sorted batch array (handles empty graphs)
__global__ void graph_bounds(const int* __restrict__ batch, int* __restrict__ gstart) {
    int i = blockIdx.x * blockDim.x + threadIdx.x;
    if (i >= N_NODES) return;
    int b  = batch[i];
    int bp = (i == 0) ? -1 : batch[i - 1];
    for (int g = bp + 1; g <= b; g++) gstart[g] = i;
    if (i == N_NODES - 1) {
        for (int g = b + 1; g <= N_GRAPHS; g++) gstart[g] = N_NODES;
    }
}

// ---------------------------------------------------------------------------
// FP32 GEMM: C[M x 128] = A[M x K] * W[K x 128]
// 64x128 block tile, 128 threads, 8x8 register tile per thread.
// A stored K-major in LDS so fragment reads are float4.
// ---------------------------------------------------------------------------
template <int K>
__global__ __launch_bounds__(128) void gemm128(const float* __restrict__ A,
                                               const float* __restrict__ W,
                                               float* __restrict__ C, int M) {
    constexpr int TM = 64, TN = 128, KC = 32;
    constexpr int AP = TM + 4;    // 68 floats: 272B, 16B-aligned rows
    constexpr int BP = TN + 4;    // 132 floats: 528B, 16B-aligned rows
    __shared__ float As[KC][AP];
    __shared__ float Bs[KC][BP];

    int tid = threadIdx.x;
    int tx = tid & 15;       // col group: cols tx*8 .. tx*8+7
    int ty = tid >> 4;       // row group: rows ty*8 .. ty*8+7
    int row0 = blockIdx.x * TM;

    float acc[8][8] = {};

    for (int k0 = 0; k0 < K; k0 += KC) {
        // Load A tile (TM x KC = 2048 floats = 512 float4; 4 per thread), transpose into LDS
#pragma unroll
        for (int j = 0; j < 4; j++) {
            int f4 = j * 128 + tid;
            int row = f4 >> 3;            // 0..63
            int kk  = (f4 & 7) * 4;       // 0..28
            int grow = row0 + row;
            float4 v = make_float4(0.f, 0.f, 0.f, 0.f);
            if (grow < M) v = *(const float4*)&A[(size_t)grow * K + k0 + kk];
            As[kk + 0][row] = v.x;
            As[kk + 1][row] = v.y;
            As[kk + 2][row] = v.z;
            As[kk + 3][row] = v.w;
        }
        // Load B tile (KC x TN = 4096 floats = 1024 float4; 8 per thread)
#pragma unroll
        for (int j = 0; j < 8; j++) {
            int f4 = j * 128 + tid;
            int kk = f4 >> 5;             // 0..31
            int c  = (f4 & 31) * 4;       // 0..124
            float4 v = *(const float4*)&W[(size_t)(k0 + kk) * TN + c];
            *(float4*)&Bs[kk][c] = v;
        }
        __syncthreads();

#pragma unroll
        for (int kk = 0; kk < KC; kk++) {
            float a[8], b[8];
            *(float4*)&a[0] = *(const float4*)&As[kk][ty * 8];
            *(float4*)&a[4] = *(const float4*)&As[kk][ty * 8 + 4];
            *(float4*)&b[0] = *(const float4*)&Bs[kk][tx * 8];
            *(float4*)&b[4] = *(const float4*)&Bs[kk][tx * 8 + 4];
#pragma unroll
            for (int r = 0; r < 8; r++)
#pragma unroll
                for (int c = 0; c < 8; c++)
                    acc[r][c] = fmaf(a[r], b[c], acc[r][c]);
        }
        __syncthreads();
    }

#pragma unroll
    for (int r = 0; r < 8; r++) {
        int row = row0 + ty * 8 + r;
        if (row < M) {
            *(float4*)&C[(size_t)row * TN + tx * 8] =
                make_float4(acc[r][0], acc[r][1], acc[r][2], acc[r][3]);
            *(float4*)&C[(size_t)row * TN + tx * 8 + 4] =
                make_float4(acc[r][4], acc[r][5], acc[r][6], acc[r][7]);
        }
    }
}

// ---------------------------------------------------------------------------
// Per-node alpha_s / alpha_d: one wave per node
// ---------------------------------------------------------------------------
__global__ __launch_bounds__(64) void compute_alpha(const float* __restrict__ h,
                                                    const float* __restrict__ a_s,
                                                    const float* __restrict__ a_d,
                                                    float* __restrict__ alpha_s,
                                                    float* __restrict__ alpha_d) {
    int n = blockIdx.x;
    int lane = threadIdx.x;
    float h0 = h[(size_t)n * HID + lane];
    float h1 = h[(size_t)n * HID + 64 + lane];
    float ps = h0 * a_s[lane] + h1 * a_s[64 + lane];
    float pd = h0 * a_d[lane] + h1 * a_d[64 + lane];
    for (int o = 32; o; o >>= 1) {
        ps += __shfl_xor(ps, o, 64);
        pd += __shfl_xor(pd, o, 64);
    }
    if (lane == 0) {
        alpha_s[n] = ps;
        alpha_d[n] = pd;
    }
}

// ---------------------------------------------------------------------------
// GAT aggregation: one wave per destination node.
// softmax over incoming edges (leaky_relu scores), weighted sum of h[src],
// + bias, ReLU.
// ---------------------------------------------------------------------------
__global__ __launch_bounds__(64) void gat_aggregate(const float* __restrict__ h,
                                                    const float* __restrict__ alpha_s,
                                                    const float* __restrict__ alpha_d,
                                                    const int* __restrict__ row_start,
                                                    const int* __restrict__ csr_src,
                                                    const float* __restrict__ bias,
                                                    float* __restrict__ out) {
    int n = blockIdx.x;
    int lane = threadIdx.x;
    int beg = row_start[n];
    int deg = row_start[n + 1] - beg;
    float adn = alpha_d[n];

    // Pass 1: max score
    float m = -INFINITY;
    for (int k = lane; k < deg; k += 64) {
        int s = csr_src[beg + k];
        float e = alpha_s[s] + adn;
        e = (e > 0.f) ? e : e * NEG_SLOPE;
        m = fmaxf(m, e);
    }
    for (int o = 32; o; o >>= 1) m = fmaxf(m, __shfl_xor(m, o, 64));

    // Pass 2: denom
    float ssum = 0.f;
    for (int k = lane; k < deg; k += 64) {
        int s = csr_src[beg + k];
        float e = alpha_s[s] + adn;
        e = (e > 0.f) ? e : e * NEG_SLOPE;
        ssum += expf(e - m);
    }
    for (int o = 32; o; o >>= 1) ssum += __shfl_xor(ssum, o, 64);
    float inv_denom = 1.f / ssum;

    // Pass 3: weighted aggregate, chunks of 64 edges via LDS coefficients
    __shared__ float coef[64];
    __shared__ int   srcs[64];
    float acc0 = 0.f, acc1 = 0.f;
    for (int c0 = 0; c0 < deg; c0 += 64) {
        int k = c0 + lane;
        if (k < deg) {
            int s = csr_src[beg + k];
            float e = alpha_s[s] + adn;
            e = (e > 0.f) ? e : e * NEG_SLOPE;
            coef[lane] = expf(e - m) * inv_denom;
            srcs[lane] = s;
        }
        __syncthreads();
        int cnt = min(64, deg - c0);
        for (int j = 0; j < cnt; j++) {
            float w = coef[j];
            size_t base = (size_t)srcs[j] * HID;
            acc0 = fmaf(w, h[base + lane], acc0);
            acc1 = fmaf(w, h[base + 64 + lane], acc1);
        }
        __syncthreads();
    }
    float o0 = fmaxf(acc0 + bias[lane], 0.f);
    float o1 = fmaxf(acc1 + bias[64 + lane], 0.f);
    out[(size_t)n * HID + lane] = o0;
    out[(size_t)n * HID + 64 + lane] = o1;
}

// ---------------------------------------------------------------------------
// Mean pool per graph (two-stage) + classifier
// ---------------------------------------------------------------------------
__global__ __launch_bounds__(128) void pool_partial(const float* __restrict__ h,
                                                    const int* __restrict__ gstart,
                                                    float* __restrict__ pool) {
    int g = blockIdx.x;
    int slice = blockIdx.y;     // 0..15
    int d = threadIdx.x;        // 0..127
    int beg = gstart[g], end = gstart[g + 1];
    float acc = 0.f;
    for (int i = beg + slice; i < end; i += 16)
        acc += h[(size_t)i * HID + d];
    atomicAdd(&pool[g * HID + d], acc);
}

__global__ __launch_bounds__(128) void classify(const float* __restrict__ pool,
                                                const int* __restrict__ gstart,
                                                const float* __restrict__ Wc,
                                                const float* __restrict__ bc,
                                                float* __restrict__ out) {
    int g = blockIdx.x;
    int d = threadIdx.x;
    float cnt = (float)(gstart[g + 1] - gstart[g]);
    float pooled = pool[g * HID + d] / fmaxf(cnt, 1.f);
    float p = pooled * Wc[d];
    __shared__ float red[2];
    for (int o = 32; o; o >>= 1) p += __shfl_xor(p, o, 64);
    if ((d & 63) == 0) red[d >> 6] = p;
    __syncthreads();
    if (d == 0) {
        float t = red[0] + red[1] + bc[0];
        out[g] = 1.f / (1.f + expf(-t));
    }
}

// ---------------------------------------------------------------------------
extern "C" void kernel_launch(void* const* d_in, const int* in_sizes, int n_in,
                              void* d_out, int out_size, void* d_ws, size_t ws_size,
                              hipStream_t stream) {
    const float* x     = (const float*)d_in[0];
    const int*   ei    = (const int*)d_in[1];    // [2, 800000]: src row then dst row
    const int*   batch = (const int*)d_in[2];
    const float* W1    = (const float*)d_in[3];
    const float* as1   = (const float*)d_in[4];
    const float* ad1   = (const float*)d_in[5];
    const float* b1    = (const float*)d_in[6];
    const float* W2    = (const float*)d_in[7];
    const float* as2   = (const float*)d_in[8];
    const float* ad2   = (const float*)d_in[9];
    const float* b2    = (const float*)d_in[10];
    const float* Wc    = (const float*)d_in[11];
    const float* bc    = (const float*)d_in[12];
    float* out = (float*)d_out;

    // Workspace carve (256B-aligned slices)
    char* p = (char*)d_ws;
    auto alloc = [&](size_t bytes) {
        void* r = (void*)p;
        p += (bytes + 255) & ~(size_t)255;
        return r;
    };
    float* h_pre   = (float*)alloc((size_t)N_NODES * HID * 4);
    float* h_buf   = (float*)alloc((size_t)N_NODES * HID * 4);
    float* alS     = (float*)alloc((size_t)N_NODES * 4);
    float* alD     = (float*)alloc((size_t)N_NODES * 4);
    int*   deg     = (int*)alloc((size_t)N_NODES * 4);
    int*   rstart  = (int*)alloc((size_t)(N_NODES + 1) * 4);
    int*   cursor  = (int*)alloc((size_t)N_NODES * 4);
    int*   csr     = (int*)alloc((size_t)E_TOT * 4);
    int*   bsums   = (int*)alloc(256 * 4);
    int*   boff    = (int*)alloc(256 * 4);
    int*   gstart  = (int*)alloc((N_GRAPHS + 1) * 4);
    float* pool    = (float*)alloc(N_GRAPHS * HID * 4);

    const int* edge_src = ei;
    const int* edge_dst = ei + N_EDGES;

    hipMemsetAsync(deg, 0, (size_t)N_NODES * 4, stream);
    hipMemsetAsync(pool, 0, (size_t)N_GRAPHS * HID * 4, stream);

    // CSR build (shared by both layers)
    count_deg<<<(E_TOT + 255) / 256, 256, 0, stream>>>(edge_dst, deg);
    scan1<<<NB_SCAN, SCAN_B, 0, stream>>>(deg, rstart, bsums);
    scan2<<<1, SCAN_B, 0, stream>>>(bsums, boff, rstart);
    scan3<<<NB_SCAN, SCAN_B, 0, stream>>>(rstart, boff, cursor);
    fill_csr<<<(E_TOT + 255) / 256, 256, 0, stream>>>(edge_src, edge_dst, cursor, csr);
    graph_bounds<<<(N_NODES + 255) / 256, 256, 0, stream>>>(batch, gstart);

    // Layer 1
    gemm128<256><<<(N_NODES + 63) / 64, 128, 0, stream>>>(x, W1, h_pre, N_NODES);
    compute_alpha<<<N_NODES, 64, 0, stream>>>(h_pre, as1, ad1, alS, alD);
    gat_aggregate<<<N_NODES, 64, 0, stream>>>(h_pre, alS, alD, rstart, csr, b1, h_buf);

    // Layer 2
    gemm128<128><<<(N_NODES + 63) / 64, 128, 0, stream>>>(h_buf, W2, h_pre, N_NODES);
    compute_alpha<<<N_NODES, 64, 0, stream>>>(h_pre, as2, ad2, alS, alD);
    gat_aggregate<<<N_NODES, 64, 0, stream>>>(h_pre, alS, alD, rstart, csr, b2, h_buf);

    // Pool + classify
    pool_partial<<<dim3(N_GRAPHS, 16), HID, 0, stream>>>(h_buf, gstart, pool);
    classify<<<N_GRAPHS, HID, 0, stream>>>(pool, gstart, Wc, bc, out);
}

// Round 2
// 352.457 us; speedup vs baseline: 1.2952x; 1.2952x over previous
//
#include <hip/hip_runtime.h>
#include <hip/hip_bf16.h>
#include <math.h>

// Problem constants (from reference)
#define N_NODES 50000
#define N_EDGES 800000
#define E_TOT   (N_EDGES + N_NODES)   // edges + self loops = 850000
#define HID     128
#define N_GRAPHS 64
#define NEG_SLOPE 0.2f

#define SCAN_B 256
#define NB_SCAN ((N_NODES + SCAN_B - 1) / SCAN_B)   // 196

typedef __attribute__((ext_vector_type(8))) short bf16x8;
typedef __attribute__((ext_vector_type(4))) float f32x4;

__device__ __forceinline__ ushort f2bf(float f) {
    union { float f; uint u; } x; x.f = f;
    uint r = x.u + 0x7fffu + ((x.u >> 16) & 1u);   // round-to-nearest-even
    return (ushort)(r >> 16);
}
__device__ __forceinline__ float bfbits2f(uint bits_hi) {
    union { uint u; float f; } x; x.u = bits_hi;
    return x.f;
}

// ---------------------------------------------------------------------------
// CSR build: count degrees -> 2-level exclusive scan -> scatter edge sources
// ---------------------------------------------------------------------------
__global__ void count_deg(const int* __restrict__ edge_dst, int* __restrict__ deg) {
    int e = blockIdx.x * blockDim.x + threadIdx.x;
    if (e >= E_TOT) return;
    int dst = (e < N_EDGES) ? edge_dst[e] : (e - N_EDGES);
    atomicAdd(&deg[dst], 1);
}

__global__ void scan1(const int* __restrict__ deg, int* __restrict__ row_start,
                      int* __restrict__ bsums) {
    __shared__ int s[SCAN_B];
    int tid = threadIdx.x;
    int i = blockIdx.x * SCAN_B + tid;
    int v = (i < N_NODES) ? deg[i] : 0;
    s[tid] = v;
    __syncthreads();
    for (int off = 1; off < SCAN_B; off <<= 1) {
        int t = (tid >= off) ? s[tid - off] : 0;
        __syncthreads();
        s[tid] += t;
        __syncthreads();
    }
    if (i < N_NODES) row_start[i] = s[tid] - v;
    if (tid == SCAN_B - 1) bsums[blockIdx.x] = s[tid];
}

__global__ void scan2(const int* __restrict__ bsums, int* __restrict__ boff,
                      int* __restrict__ row_start) {
    __shared__ int s[SCAN_B];
    int tid = threadIdx.x;
    int v = (tid < NB_SCAN) ? bsums[tid] : 0;
    s[tid] = v;
    __syncthreads();
    for (int off = 1; off < SCAN_B; off <<= 1) {
        int t = (tid >= off) ? s[tid - off] : 0;
        __syncthreads();
        s[tid] += t;
        __syncthreads();
    }
    if (tid < NB_SCAN) boff[tid] = s[tid] - v;
    if (tid == SCAN_B - 1) row_start[N_NODES] = s[tid];
}

__global__ void scan3(int* __restrict__ row_start, const int* __restrict__ boff,
                      int* __restrict__ cursor) {
    int i = blockIdx.x * SCAN_B + threadIdx.x;
    if (i >= N_NODES) return;
    int r = row_start[i] + boff[blockIdx.x];
    row_start[i] = r;
    cursor[i] = r;
}

__global__ void fill_csr(const int* __restrict__ edge_src, const int* __restrict__ edge_dst,
                         int* __restrict__ cursor, int* __restrict__ csr_src) {
    int e = blockIdx.x * blockDim.x + threadIdx.x;
    if (e >= E_TOT) return;
    int s, d;
    if (e < N_EDGES) { s = edge_src[e]; d = edge_dst[e]; }
    else             { s = d = e - N_EDGES; }
    int pos = atomicAdd(&cursor[d], 1);
    csr_src[pos] = s;
}

__global__ void graph_bounds(const int* __restrict__ batch, int* __restrict__ gstart) {
    int i = blockIdx.x * blockDim.x + threadIdx.x;
    if (i >= N_NODES) return;
    int b  = batch[i];
    int bp = (i == 0) ? -1 : batch[i - 1];
    for (int g = bp + 1; g <= b; g++) gstart[g] = i;
    if (i == N_NODES - 1) {
        for (int g = b + 1; g <= N_GRAPHS; g++) gstart[g] = N_NODES;
    }
}

// Transpose + convert weights: W[K][128] fp32 -> Wt[128][K] bf16
template <int K>
__global__ void convW(const float* __restrict__ W, ushort* __restrict__ Wt) {
    int idx = blockIdx.x * 256 + threadIdx.x;
    if (idx >= K * 128) return;
    int k = idx >> 7, n = idx & 127;
    Wt[n * K + k] = f2bf(W[idx]);
}

// ---------------------------------------------------------------------------
// BF16 MFMA GEMM: Cbf[M x 128] = bf16(A[M x K]) * Wt^T   (Wt is [128][K] bf16)
// 64x128 block tile, 256 threads = 4 waves; wave w does rows 16w..16w+15.
// KC=64 (2 mfma k-steps), LDS rows padded to 72 bf16 (2-way conflicts only).
// ---------------------------------------------------------------------------
template <int K>
__global__ __launch_bounds__(256) void gemm_mfma(const float* __restrict__ A,
                                                 const ushort* __restrict__ Wt,
                                                 ushort* __restrict__ Cbf, int M) {
    constexpr int KC = 64;
    constexpr int AP = 72;                 // padded k-stride (bf16 elems)
    __shared__ ushort As[64 * AP];         //  9216 B
    __shared__ ushort Bs[128 * AP];        // 18432 B

    int tid = threadIdx.x;
    int lane = tid & 63;
    int wv = tid >> 6;
    int mrow = lane & 15;
    int quad = lane >> 4;
    int row0 = blockIdx.x * 64;

    f32x4 acc[8];
#pragma unroll
    for (int t = 0; t < 8; t++) acc[t] = (f32x4){0.f, 0.f, 0.f, 0.f};

    for (int k0 = 0; k0 < K; k0 += KC) {
        // Stage A tile: 64 rows x 64 k, fp32 -> bf16. 512 chunks of 8 elems.
#pragma unroll
        for (int p = 0; p < 2; p++) {
            int c = p * 256 + tid;
            int r = c >> 3;
            int kk = (c & 7) * 8;
            int grow = row0 + r;
            float4 v0 = make_float4(0.f, 0.f, 0.f, 0.f);
            float4 v1 = v0;
            if (grow < M) {
                const float* src = &A[(size_t)grow * K + k0 + kk];
                v0 = *(const float4*)src;
                v1 = *(const float4*)(src + 4);
            }
            uint4 w;
            w.x = (uint)f2bf(v0.x) | ((uint)f2bf(v0.y) << 16);
            w.y = (uint)f2bf(v0.z) | ((uint)f2bf(v0.w) << 16);
            w.z = (uint)f2bf(v1.x) | ((uint)f2bf(v1.y) << 16);
            w.w = (uint)f2bf(v1.z) | ((uint)f2bf(v1.w) << 16);
            *(uint4*)&As[r * AP + kk] = w;
        }
        // Stage B tile: 128 n-rows x 64 k (already bf16, k-contiguous).
#pragma unroll
        for (int p = 0; p < 4; p++) {
            int c = p * 256 + tid;
            int n = c >> 3;
            int kk = (c & 7) * 8;
            uint4 v = *(const uint4*)&Wt[(size_t)n * K + k0 + kk];
            *(uint4*)&Bs[n * AP + kk] = v;
        }
        __syncthreads();

        const ushort* arow = &As[(wv * 16 + mrow) * AP + quad * 8];
        const ushort* brow = &Bs[mrow * AP + quad * 8];
#pragma unroll
        for (int ks = 0; ks < KC; ks += 32) {
            bf16x8 a = *(const bf16x8*)&arow[ks];
#pragma unroll
            for (int t = 0; t < 8; t++) {
                bf16x8 b = *(const bf16x8*)&brow[t * 16 * AP + ks];
                acc[t] = __builtin_amdgcn_mfma_f32_16x16x32_bf16(a, b, acc[t], 0, 0, 0);
            }
        }
        __syncthreads();
    }

    // Epilogue: C/D layout col=lane&15, row=quad*4+reg
#pragma unroll
    for (int t = 0; t < 8; t++) {
#pragma unroll
        for (int r = 0; r < 4; r++) {
            int row = row0 + wv * 16 + quad * 4 + r;
            if (row < M)
                Cbf[(size_t)row * HID + t * 16 + mrow] = f2bf(acc[t][r]);
        }
    }
}

// ---------------------------------------------------------------------------
// Per-node alpha_s / alpha_d from bf16 h: one wave per node, 2 cols/lane
// ---------------------------------------------------------------------------
__global__ __launch_bounds__(64) void compute_alpha(const ushort* __restrict__ hbf,
                                                    const float* __restrict__ a_s,
                                                    const float* __restrict__ a_d,
                                                    float* __restrict__ alpha_s,
                                                    float* __restrict__ alpha_d) {
    int n = blockIdx.x;
    int l = threadIdx.x;
    uint v = *(const uint*)&hbf[(size_t)n * HID + 2 * l];
    float f0 = bfbits2f(v << 16);
    float f1 = bfbits2f(v & 0xffff0000u);
    float2 s = *(const float2*)&a_s[2 * l];
    float2 d = *(const float2*)&a_d[2 * l];
    float ps = f0 * s.x + f1 * s.y;
    float pd = f0 * d.x + f1 * d.y;
    for (int o = 32; o; o >>= 1) {
        ps += __shfl_xor(ps, o, 64);
        pd += __shfl_xor(pd, o, 64);
    }
    if (l == 0) {
        alpha_s[n] = ps;
        alpha_d[n] = pd;
    }
}

// ---------------------------------------------------------------------------
// GAT aggregation: one wave per destination node, bf16 gathers (2 cols/lane).
// ---------------------------------------------------------------------------
__global__ __launch_bounds__(64) void gat_aggregate(const ushort* __restrict__ hbf,
                                                    const float* __restrict__ alpha_s,
                                                    const float* __restrict__ alpha_d,
                                                    const int* __restrict__ row_start,
                                                    const int* __restrict__ csr_src,
                                                    const float* __restrict__ bias,
                                                    float* __restrict__ out) {
    int n = blockIdx.x;
    int lane = threadIdx.x;
    int beg = row_start[n];
    int deg = row_start[n + 1] - beg;
    float adn = alpha_d[n];

    // Pass 1: max score
    float m = -INFINITY;
    for (int k = lane; k < deg; k += 64) {
        int s = csr_src[beg + k];
        float e = alpha_s[s] + adn;
        e = (e > 0.f) ? e : e * NEG_SLOPE;
        m = fmaxf(m, e);
    }
    for (int o = 32; o; o >>= 1) m = fmaxf(m, __shfl_xor(m, o, 64));

    // Pass 2: denom
    float ssum = 0.f;
    for (int k = lane; k < deg; k += 64) {
        int s = csr_src[beg + k];
        float e = alpha_s[s] + adn;
        e = (e > 0.f) ? e : e * NEG_SLOPE;
        ssum += __expf(e - m);
    }
    for (int o = 32; o; o >>= 1) ssum += __shfl_xor(ssum, o, 64);
    float inv_denom = 1.f / ssum;

    // Pass 3: weighted aggregate; lane owns cols 2*lane, 2*lane+1
    __shared__ float coef[64];
    __shared__ int   srcs[64];
    float acc0 = 0.f, acc1 = 0.f;
    for (int c0 = 0; c0 < deg; c0 += 64) {
        int k = c0 + lane;
        if (k < deg) {
            int s = csr_src[beg + k];
            float e = alpha_s[s] + adn;
            e = (e > 0.f) ? e : e * NEG_SLOPE;
            coef[lane] = __expf(e - m) * inv_denom;
            srcs[lane] = s;
        }
        __syncthreads();
        int cnt = min(64, deg - c0);
#pragma unroll 4
        for (int j = 0; j < cnt; j++) {
            float w = coef[j];
            uint v = *(const uint*)&hbf[(size_t)srcs[j] * HID + 2 * lane];
            acc0 = fmaf(w, bfbits2f(v << 16), acc0);
            acc1 = fmaf(w, bfbits2f(v & 0xffff0000u), acc1);
        }
        __syncthreads();
    }
    float2 bv = *(const float2*)&bias[2 * lane];
    float2 o2;
    o2.x = fmaxf(acc0 + bv.x, 0.f);
    o2.y = fmaxf(acc1 + bv.y, 0.f);
    *(float2*)&out[(size_t)n * HID + 2 * lane] = o2;
}

// ---------------------------------------------------------------------------
// Mean pool per graph (two-stage) + classifier
// ---------------------------------------------------------------------------
__global__ __launch_bounds__(128) void pool_partial(const float* __restrict__ h,
                                                    const int* __restrict__ gstart,
                                                    float* __restrict__ pool) {
    int g = blockIdx.x;
    int slice = blockIdx.y;
    int d = threadIdx.x;
    int beg = gstart[g], end = gstart[g + 1];
    float acc = 0.f;
    for (int i = beg + slice; i < end; i += 16)
        acc += h[(size_t)i * HID + d];
    atomicAdd(&pool[g * HID + d], acc);
}

__global__ __launch_bounds__(128) void classify(const float* __restrict__ pool,
                                                const int* __restrict__ gstart,
                                                const float* __restrict__ Wc,
                                                const float* __restrict__ bc,
                                                float* __restrict__ out) {
    int g = blockIdx.x;
    int d = threadIdx.x;
    float cnt = (float)(gstart[g + 1] - gstart[g]);
    float pooled = pool[g * HID + d] / fmaxf(cnt, 1.f);
    float p = pooled * Wc[d];
    __shared__ float red[2];
    for (int o = 32; o; o >>= 1) p += __shfl_xor(p, o, 64);
    if ((d & 63) == 0) red[d >> 6] = p;
    __syncthreads();
    if (d == 0) {
        float t = red[0] + red[1] + bc[0];
        out[g] = 1.f / (1.f + expf(-t));
    }
}

// ---------------------------------------------------------------------------
extern "C" void kernel_launch(void* const* d_in, const int* in_sizes, int n_in,
                              void* d_out, int out_size, void* d_ws, size_t ws_size,
                              hipStream_t stream) {
    const float* x     = (const float*)d_in[0];
    const int*   ei    = (const int*)d_in[1];
    const int*   batch = (const int*)d_in[2];
    const float* W1    = (const float*)d_in[3];
    const float* as1   = (const float*)d_in[4];
    const float* ad1   = (const float*)d_in[5];
    const float* b1    = (const float*)d_in[6];
    const float* W2    = (const float*)d_in[7];
    const float* as2   = (const float*)d_in[8];
    const float* ad2   = (const float*)d_in[9];
    const float* b2    = (const float*)d_in[10];
    const float* Wc    = (const float*)d_in[11];
    const float* bc    = (const float*)d_in[12];
    float* out = (float*)d_out;

    char* p = (char*)d_ws;
    auto alloc = [&](size_t bytes) {
        void* r = (void*)p;
        p += (bytes + 255) & ~(size_t)255;
        return r;
    };
    ushort* h_bf   = (ushort*)alloc((size_t)N_NODES * HID * 2);   // 12.8 MB
    float*  h_buf  = (float*)alloc((size_t)N_NODES * HID * 4);    // 25.6 MB
    float*  alS    = (float*)alloc((size_t)N_NODES * 4);
    float*  alD    = (float*)alloc((size_t)N_NODES * 4);
    int*    deg    = (int*)alloc((size_t)N_NODES * 4);
    int*    rstart = (int*)alloc((size_t)(N_NODES + 1) * 4);
    int*    cursor = (int*)alloc((size_t)N_NODES * 4);
    int*    csr    = (int*)alloc((size_t)E_TOT * 4);
    int*    bsums  = (int*)alloc(256 * 4);
    int*    boff   = (int*)alloc(256 * 4);
    int*    gstart = (int*)alloc((N_GRAPHS + 1) * 4);
    float*  pool   = (float*)alloc(N_GRAPHS * HID * 4);
    ushort* Wt1    = (ushort*)alloc((size_t)128 * 256 * 2);
    ushort* Wt2    = (ushort*)alloc((size_t)128 * 128 * 2);

    const int* edge_src = ei;
    const int* edge_dst = ei + N_EDGES;

    hipMemsetAsync(deg, 0, (size_t)N_NODES * 4, stream);
    hipMemsetAsync(pool, 0, (size_t)N_GRAPHS * HID * 4, stream);

    // Weight prep + CSR build
    convW<256><<<(256 * 128 + 255) / 256, 256, 0, stream>>>(W1, Wt1);
    convW<128><<<(128 * 128 + 255) / 256, 256, 0, stream>>>(W2, Wt2);
    count_deg<<<(E_TOT + 255) / 256, 256, 0, stream>>>(edge_dst, deg);
    scan1<<<NB_SCAN, SCAN_B, 0, stream>>>(deg, rstart, bsums);
    scan2<<<1, SCAN_B, 0, stream>>>(bsums, boff, rstart);
    scan3<<<NB_SCAN, SCAN_B, 0, stream>>>(rstart, boff, cursor);
    fill_csr<<<(E_TOT + 255) / 256, 256, 0, stream>>>(edge_src, edge_dst, cursor, csr);
    graph_bounds<<<(N_NODES + 255) / 256, 256, 0, stream>>>(batch, gstart);

    // Layer 1
    gemm_mfma<256><<<(N_NODES + 63) / 64, 256, 0, stream>>>(x, Wt1, h_bf, N_NODES);
    compute_alpha<<<N_NODES, 64, 0, stream>>>(h_bf, as1, ad1, alS, alD);
    gat_aggregate<<<N_NODES, 64, 0, stream>>>(h_bf, alS, alD, rstart, csr, b1, h_buf);

    // Layer 2
    gemm_mfma<128><<<(N_NODES + 63) / 64, 256, 0, stream>>>(h_buf, Wt2, h_bf, N_NODES);
    compute_alpha<<<N_NODES, 64, 0, stream>>>(h_bf, as2, ad2, alS, alD);
    gat_aggregate<<<N_NODES, 64, 0, stream>>>(h_bf, alS, alD, rstart, csr, b2, h_buf);

    // Pool + classify
    pool_partial<<<dim3(N_GRAPHS, 16), HID, 0, stream>>>(h_buf, gstart, pool);
    classify<<<N_GRAPHS, HID, 0, stream>>>(pool, gstart, Wc, bc, out);
}

// Round 3
// 274.708 us; speedup vs baseline: 1.6618x; 1.2830x over previous
//
#include <hip/hip_runtime.h>
#include <hip/hip_bf16.h>
#include <math.h>

// Problem constants (from reference)
#define N_NODES 50000
#define N_EDGES 800000
#define E_TOT   (N_EDGES + N_NODES)   // edges + self loops = 850000
#define HID     128
#define N_GRAPHS 64
#define NEG_SLOPE 0.2f

// Radix partition params
#define NBKT 196                      // buckets of 256 dst nodes (50000/256 -> 196)
#define EPB1 2048
#define NB1  ((E_TOT + EPB1 - 1) / EPB1)      // 416
#define CHUNK 4096
#define NB3  ((E_TOT + CHUNK - 1) / CHUNK)    // 208
#define CAP4 6144                     // P4 LDS pair cache (mean ~4340, >25 sigma slack)

typedef __attribute__((ext_vector_type(8))) short bf16x8;
typedef __attribute__((ext_vector_type(4))) float f32x4;

__device__ __forceinline__ ushort f2bf(float f) {
    union { float f; uint u; } x; x.f = f;
    uint r = x.u + 0x7fffu + ((x.u >> 16) & 1u);   // round-to-nearest-even
    return (ushort)(r >> 16);
}
__device__ __forceinline__ float bfbits2f(uint bits_hi) {
    union { uint u; float f; } x; x.u = bits_hi;
    return x.f;
}

// ---------------------------------------------------------------------------
// P1: per-block LDS histogram of dst buckets -> global bucket counts
// ---------------------------------------------------------------------------
__global__ __launch_bounds__(256) void bin_count(const int* __restrict__ edge_dst,
                                                 int* __restrict__ bcnt) {
    __shared__ int hist[256];
    int tid = threadIdx.x;
    hist[tid] = 0;
    __syncthreads();
    int start = blockIdx.x * EPB1;
    int end = min(start + EPB1, E_TOT);
    for (int e = start + tid; e < end; e += 256) {
        int d = (e < N_EDGES) ? edge_dst[e] : (e - N_EDGES);
        atomicAdd(&hist[d >> 8], 1);
    }
    __syncthreads();
    if (tid < NBKT && hist[tid]) atomicAdd(&bcnt[tid], hist[tid]);
}

// ---------------------------------------------------------------------------
// P2: exclusive scan over bucket counts -> bucket bases + global cursors
// ---------------------------------------------------------------------------
__global__ __launch_bounds__(256) void bucket_scan(const int* __restrict__ bcnt,
                                                   int* __restrict__ bbase,
                                                   int* __restrict__ gcur,
                                                   int* __restrict__ row_start) {
    __shared__ int s[256];
    int tid = threadIdx.x;
    int v = (tid < NBKT) ? bcnt[tid] : 0;
    s[tid] = v;
    __syncthreads();
    for (int off = 1; off < 256; off <<= 1) {
        int t = (tid >= off) ? s[tid - off] : 0;
        __syncthreads();
        s[tid] += t;
        __syncthreads();
    }
    if (tid < NBKT) { bbase[tid] = s[tid] - v; gcur[tid] = s[tid] - v; }
    if (tid == 255) { bbase[NBKT] = s[255]; row_start[N_NODES] = s[255]; }
}

// ---------------------------------------------------------------------------
// P3: block-local bucket ordering in LDS, then coalesced run writes to staging
// ---------------------------------------------------------------------------
__global__ __launch_bounds__(256) void bin_scatter(const int* __restrict__ edge_src,
                                                   const int* __restrict__ edge_dst,
                                                   int* __restrict__ gcur,
                                                   uint2* __restrict__ staged) {
    __shared__ int hist[256], base_l[256], cur[256], runbase[256], scan_s[256];
    __shared__ uint2 pairs[CHUNK];
    int tid = threadIdx.x;
    int e0 = blockIdx.x * CHUNK;
    int cnt = min(CHUNK, E_TOT - e0);

    hist[tid] = 0;
    __syncthreads();
    // pass 1: histogram
    for (int i = tid; i < cnt; i += 256) {
        int e = e0 + i;
        int d = (e < N_EDGES) ? edge_dst[e] : (e - N_EDGES);
        atomicAdd(&hist[d >> 8], 1);
    }
    __syncthreads();
    // exclusive scan
    int v = hist[tid];
    scan_s[tid] = v;
    __syncthreads();
    for (int off = 1; off < 256; off <<= 1) {
        int t = (tid >= off) ? scan_s[tid - off] : 0;
        __syncthreads();
        scan_s[tid] += t;
        __syncthreads();
    }
    base_l[tid] = scan_s[tid] - v;
    cur[tid] = scan_s[tid] - v;
    __syncthreads();
    // pass 2: scatter pairs into bucket-grouped LDS order
    for (int i = tid; i < cnt; i += 256) {
        int e = e0 + i;
        int s, d;
        if (e < N_EDGES) { s = edge_src[e]; d = edge_dst[e]; }
        else             { s = d = e - N_EDGES; }
        int p = atomicAdd(&cur[d >> 8], 1);
        pairs[p] = make_uint2((uint)s, (uint)d);
    }
    __syncthreads();
    // reserve global runs (one atomic per non-empty bucket)
    if (tid < NBKT && hist[tid] > 0) runbase[tid] = atomicAdd(&gcur[tid], hist[tid]);
    __syncthreads();
    // copy out: consecutive i within a bucket -> consecutive global positions
    for (int i = tid; i < cnt; i += 256) {
        uint2 pr = pairs[i];
        int b = (int)(pr.y >> 8);
        staged[runbase[b] + (i - base_l[b])] = pr;
    }
}

// ---------------------------------------------------------------------------
// P4: one block per bucket; per-node CSR within the bucket's contiguous region
// ---------------------------------------------------------------------------
__global__ __launch_bounds__(256) void bucket_build(const uint2* __restrict__ staged,
                                                    const int* __restrict__ bbase,
                                                    int* __restrict__ row_start,
                                                    int* __restrict__ csr_src) {
    __shared__ int hist[256], base_l[256], scan_s[256];
    __shared__ uint2 lpairs[CAP4];
    int tid = threadIdx.x;
    int b = blockIdx.x;
    int base = bbase[b];
    int cnt = bbase[b + 1] - base;

    hist[tid] = 0;
    __syncthreads();
    for (int i = tid; i < cnt; i += 256) {
        uint2 pr = staged[base + i];
        if (i < CAP4) lpairs[i] = pr;
        atomicAdd(&hist[pr.y & 255], 1);
    }
    __syncthreads();
    int v = hist[tid];
    scan_s[tid] = v;
    __syncthreads();
    for (int off = 1; off < 256; off <<= 1) {
        int t = (tid >= off) ? scan_s[tid - off] : 0;
        __syncthreads();
        scan_s[tid] += t;
        __syncthreads();
    }
    int excl = scan_s[tid] - v;
    base_l[tid] = excl;
    int node = b * 256 + tid;
    if (node < N_NODES) row_start[node] = base + excl;
    __syncthreads();
    // scatter src values; writes confined to this bucket's ~18KB region
    for (int i = tid; i < cnt; i += 256) {
        uint2 pr = (i < CAP4) ? lpairs[i] : staged[base + i];
        int pos = base + atomicAdd(&base_l[pr.y & 255], 1);
        csr_src[pos] = (int)pr.x;
    }
}

// Graph boundaries from sorted batch array (handles empty graphs)
__global__ void graph_bounds(const int* __restrict__ batch, int* __restrict__ gstart) {
    int i = blockIdx.x * blockDim.x + threadIdx.x;
    if (i >= N_NODES) return;
    int b  = batch[i];
    int bp = (i == 0) ? -1 : batch[i - 1];
    for (int g = bp + 1; g <= b; g++) gstart[g] = i;
    if (i == N_NODES - 1) {
        for (int g = b + 1; g <= N_GRAPHS; g++) gstart[g] = N_NODES;
    }
}

// Transpose + convert weights: W[K][128] fp32 -> Wt[128][K] bf16
template <int K>
__global__ void convW(const float* __restrict__ W, ushort* __restrict__ Wt) {
    int idx = blockIdx.x * 256 + threadIdx.x;
    if (idx >= K * 128) return;
    int k = idx >> 7, n = idx & 127;
    Wt[n * K + k] = f2bf(W[idx]);
}

// ---------------------------------------------------------------------------
// BF16 MFMA GEMM + fused alpha epilogue.
// C[M x 128] = bf16(A[M x K]) * Wt^T; also alpha_s/d[row] = dot(C_row, a_s/d).
// A is fp32 (layer 1) or bf16 (layer 2).
// ---------------------------------------------------------------------------
template <int K, bool ABF>
__global__ __launch_bounds__(256) void gemm_mfma(const void* __restrict__ Aptr,
                                                 const ushort* __restrict__ Wt,
                                                 ushort* __restrict__ Cbf,
                                                 const float* __restrict__ a_sv,
                                                 const float* __restrict__ a_dv,
                                                 float* __restrict__ alpha_s,
                                                 float* __restrict__ alpha_d, int M) {
    constexpr int KC = 64;
    constexpr int AP = 72;                 // padded k-stride (bf16 elems)
    __shared__ ushort As[64 * AP];
    __shared__ ushort Bs[128 * AP];

    int tid = threadIdx.x;
    int lane = tid & 63;
    int wv = tid >> 6;
    int mrow = lane & 15;
    int quad = lane >> 4;
    int row0 = blockIdx.x * 64;

    f32x4 acc[8];
#pragma unroll
    for (int t = 0; t < 8; t++) acc[t] = (f32x4){0.f, 0.f, 0.f, 0.f};

    for (int k0 = 0; k0 < K; k0 += KC) {
        if constexpr (!ABF) {
            const float* A = (const float*)Aptr;
#pragma unroll
            for (int p = 0; p < 2; p++) {
                int c = p * 256 + tid;
                int r = c >> 3;
                int kk = (c & 7) * 8;
                int grow = row0 + r;
                float4 v0 = make_float4(0.f, 0.f, 0.f, 0.f);
                float4 v1 = v0;
                if (grow < M) {
                    const float* src = &A[(size_t)grow * K + k0 + kk];
                    v0 = *(const float4*)src;
                    v1 = *(const float4*)(src + 4);
                }
                uint4 w;
                w.x = (uint)f2bf(v0.x) | ((uint)f2bf(v0.y) << 16);
                w.y = (uint)f2bf(v0.z) | ((uint)f2bf(v0.w) << 16);
                w.z = (uint)f2bf(v1.x) | ((uint)f2bf(v1.y) << 16);
                w.w = (uint)f2bf(v1.z) | ((uint)f2bf(v1.w) << 16);
                *(uint4*)&As[r * AP + kk] = w;
            }
        } else {
            const ushort* A = (const ushort*)Aptr;
#pragma unroll
            for (int p = 0; p < 2; p++) {
                int c = p * 256 + tid;
                int r = c >> 3;
                int kk = (c & 7) * 8;
                int grow = row0 + r;
                uint4 v = make_uint4(0, 0, 0, 0);
                if (grow < M) v = *(const uint4*)&A[(size_t)grow * K + k0 + kk];
                *(uint4*)&As[r * AP + kk] = v;
            }
        }
#pragma unroll
        for (int p = 0; p < 4; p++) {
            int c = p * 256 + tid;
            int n = c >> 3;
            int kk = (c & 7) * 8;
            uint4 v = *(const uint4*)&Wt[(size_t)n * K + k0 + kk];
            *(uint4*)&Bs[n * AP + kk] = v;
        }
        __syncthreads();

        const ushort* arow = &As[(wv * 16 + mrow) * AP + quad * 8];
        const ushort* brow = &Bs[mrow * AP + quad * 8];
#pragma unroll
        for (int ks = 0; ks < KC; ks += 32) {
            bf16x8 a = *(const bf16x8*)&arow[ks];
#pragma unroll
            for (int t = 0; t < 8; t++) {
                bf16x8 b = *(const bf16x8*)&brow[t * 16 * AP + ks];
                acc[t] = __builtin_amdgcn_mfma_f32_16x16x32_bf16(a, b, acc[t], 0, 0, 0);
            }
        }
        __syncthreads();
    }

    // Fused alpha epilogue: per-row dot with a_src / a_dst (fp32 accs)
    float as_r[8], ad_r[8];
#pragma unroll
    for (int t = 0; t < 8; t++) {
        int col = t * 16 + mrow;
        as_r[t] = a_sv[col];
        ad_r[t] = a_dv[col];
    }
#pragma unroll
    for (int r = 0; r < 4; r++) {
        float ps = 0.f, pd = 0.f;
#pragma unroll
        for (int t = 0; t < 8; t++) {
            ps = fmaf(acc[t][r], as_r[t], ps);
            pd = fmaf(acc[t][r], ad_r[t], pd);
        }
#pragma unroll
        for (int o = 1; o < 16; o <<= 1) {
            ps += __shfl_xor(ps, o, 64);
            pd += __shfl_xor(pd, o, 64);
        }
        int row = row0 + wv * 16 + quad * 4 + r;
        if (mrow == 0 && row < M) {
            alpha_s[row] = ps;
            alpha_d[row] = pd;
        }
    }

    // C write (C/D layout: col=lane&15, row=quad*4+reg)
#pragma unroll
    for (int t = 0; t < 8; t++) {
#pragma unroll
        for (int r = 0; r < 4; r++) {
            int row = row0 + wv * 16 + quad * 4 + r;
            if (row < M)
                Cbf[(size_t)row * HID + t * 16 + mrow] = f2bf(acc[t][r]);
        }
    }
}

// ---------------------------------------------------------------------------
// GAT aggregation: one wave per destination node, online softmax (2 sweeps),
// bf16 gathers, bf16 output (bias + ReLU fused).
// ---------------------------------------------------------------------------
__global__ __launch_bounds__(64) void gat_aggregate(const ushort* __restrict__ hbf,
                                                    const float* __restrict__ alpha_s,
                                                    const float* __restrict__ alpha_d,
                                                    const int* __restrict__ row_start,
                                                    const int* __restrict__ csr_src,
                                                    const float* __restrict__ bias,
                                                    ushort* __restrict__ outbf) {
    int n = blockIdx.x;
    int lane = threadIdx.x;
    int beg = row_start[n];
    int deg = row_start[n + 1] - beg;
    float adn = alpha_d[n];

    // Single sweep: online max + rescaled sum
    float m = -1e30f, ssum = 0.f;
    for (int k = lane; k < deg; k += 64) {
        int s = csr_src[beg + k];
        float e = alpha_s[s] + adn;
        e = (e > 0.f) ? e : e * NEG_SLOPE;
        float mo = m;
        m = fmaxf(m, e);
        ssum = ssum * __expf(mo - m) + __expf(e - m);
    }
    for (int o = 32; o; o >>= 1) {
        float m2 = __shfl_xor(m, o, 64);
        float s2 = __shfl_xor(ssum, o, 64);
        float mn = fmaxf(m, m2);
        ssum = ssum * __expf(m - mn) + s2 * __expf(m2 - mn);
        m = mn;
    }
    float inv_denom = 1.f / ssum;

    // Weighted aggregate; lane owns cols 2*lane, 2*lane+1
    __shared__ float coef[64];
    __shared__ int   srcs[64];
    float acc0 = 0.f, acc1 = 0.f;
    for (int c0 = 0; c0 < deg; c0 += 64) {
        int k = c0 + lane;
        if (k < deg) {
            int s = csr_src[beg + k];
            float e = alpha_s[s] + adn;
            e = (e > 0.f) ? e : e * NEG_SLOPE;
            coef[lane] = __expf(e - m) * inv_denom;
            srcs[lane] = s;
        }
        __syncthreads();
        int cnt = min(64, deg - c0);
#pragma unroll 4
        for (int j = 0; j < cnt; j++) {
            float w = coef[j];
            uint v = *(const uint*)&hbf[(size_t)srcs[j] * HID + 2 * lane];
            acc0 = fmaf(w, bfbits2f(v << 16), acc0);
            acc1 = fmaf(w, bfbits2f(v & 0xffff0000u), acc1);
        }
        __syncthreads();
    }
    float2 bv = *(const float2*)&bias[2 * lane];
    float o0 = fmaxf(acc0 + bv.x, 0.f);
    float o1 = fmaxf(acc1 + bv.y, 0.f);
    uint pk = (uint)f2bf(o0) | ((uint)f2bf(o1) << 16);
    *(uint*)&outbf[(size_t)n * HID + 2 * lane] = pk;
}

// ---------------------------------------------------------------------------
// Mean pool per graph (two-stage, bf16 input) + classifier
// ---------------------------------------------------------------------------
__global__ __launch_bounds__(128) void pool_partial(const ushort* __restrict__ h,
                                                    const int* __restrict__ gstart,
                                                    float* __restrict__ pool) {
    int g = blockIdx.x;
    int slice = blockIdx.y;
    int d = threadIdx.x;
    int beg = gstart[g], end = gstart[g + 1];
    float acc = 0.f;
    for (int i = beg + slice; i < end; i += 16)
        acc += bfbits2f(((uint)h[(size_t)i * HID + d]) << 16);
    atomicAdd(&pool[g * HID + d], acc);
}

__global__ __launch_bounds__(128) void classify(const float* __restrict__ pool,
                                                const int* __restrict__ gstart,
                                                const float* __restrict__ Wc,
                                                const float* __restrict__ bc,
                                                float* __restrict__ out) {
    int g = blockIdx.x;
    int d = threadIdx.x;
    float cnt = (float)(gstart[g + 1] - gstart[g]);
    float pooled = pool[g * HID + d] / fmaxf(cnt, 1.f);
    float p = pooled * Wc[d];
    __shared__ float red[2];
    for (int o = 32; o; o >>= 1) p += __shfl_xor(p, o, 64);
    if ((d & 63) == 0) red[d >> 6] = p;
    __syncthreads();
    if (d == 0) {
        float t = red[0] + red[1] + bc[0];
        out[g] = 1.f / (1.f + expf(-t));
    }
}

// ---------------------------------------------------------------------------
extern "C" void kernel_launch(void* const* d_in, const int* in_sizes, int n_in,
                              void* d_out, int out_size, void* d_ws, size_t ws_size,
                              hipStream_t stream) {
    const float* x     = (const float*)d_in[0];
    const int*   ei    = (const int*)d_in[1];
    const int*   batch = (const int*)d_in[2];
    const float* W1    = (const float*)d_in[3];
    const float* as1   = (const float*)d_in[4];
    const float* ad1   = (const float*)d_in[5];
    const float* b1    = (const float*)d_in[6];
    const float* W2    = (const float*)d_in[7];
    const float* as2   = (const float*)d_in[8];
    const float* ad2   = (const float*)d_in[9];
    const float* b2    = (const float*)d_in[10];
    const float* Wc    = (const float*)d_in[11];
    const float* bc    = (const float*)d_in[12];
    float* out = (float*)d_out;

    char* p = (char*)d_ws;
    auto alloc = [&](size_t bytes) {
        void* r = (void*)p;
        p += (bytes + 255) & ~(size_t)255;
        return r;
    };
    ushort* h0     = (ushort*)alloc((size_t)N_NODES * HID * 2);   // gemm1 out / agg2 out
    ushort* h1     = (ushort*)alloc((size_t)N_NODES * HID * 2);   // agg1 out
    ushort* h2     = (ushort*)alloc((size_t)N_NODES * HID * 2);   // gemm2 out
    float*  alS    = (float*)alloc((size_t)N_NODES * 4);
    float*  alD    = (float*)alloc((size_t)N_NODES * 4);
    uint2*  staged = (uint2*)alloc((size_t)E_TOT * 8);            // 6.8 MB
    int*    csr    = (int*)alloc((size_t)E_TOT * 4);              // 3.4 MB
    int*    rstart = (int*)alloc((size_t)(N_NODES + 1) * 4);
    int*    bcnt   = (int*)alloc((NBKT + 1) * 4);
    int*    bbase  = (int*)alloc((NBKT + 1) * 4);
    int*    gcur   = (int*)alloc((NBKT + 1) * 4);
    int*    gstart = (int*)alloc((N_GRAPHS + 1) * 4);
    float*  pool   = (float*)alloc(N_GRAPHS * HID * 4);
    ushort* Wt1    = (ushort*)alloc((size_t)128 * 256 * 2);
    ushort* Wt2    = (ushort*)alloc((size_t)128 * 128 * 2);

    const int* edge_src = ei;
    const int* edge_dst = ei + N_EDGES;

    hipMemsetAsync(bcnt, 0, (NBKT + 1) * 4, stream);
    hipMemsetAsync(pool, 0, (size_t)N_GRAPHS * HID * 4, stream);

    // Weight prep + radix-partition CSR build
    convW<256><<<(256 * 128 + 255) / 256, 256, 0, stream>>>(W1, Wt1);
    convW<128><<<(128 * 128 + 255) / 256, 256, 0, stream>>>(W2, Wt2);
    bin_count<<<NB1, 256, 0, stream>>>(edge_dst, bcnt);
    bucket_scan<<<1, 256, 0, stream>>>(bcnt, bbase, gcur, rstart);
    bin_scatter<<<NB3, 256, 0, stream>>>(edge_src, edge_dst, gcur, staged);
    bucket_build<<<NBKT, 256, 0, stream>>>(staged, bbase, rstart, csr);
    graph_bounds<<<(N_NODES + 255) / 256, 256, 0, stream>>>(batch, gstart);

    // Layer 1
    gemm_mfma<256, false><<<(N_NODES + 63) / 64, 256, 0, stream>>>(
        x, Wt1, h0, as1, ad1, alS, alD, N_NODES);
    gat_aggregate<<<N_NODES, 64, 0, stream>>>(h0, alS, alD, rstart, csr, b1, h1);

    // Layer 2
    gemm_mfma<128, true><<<(N_NODES + 63) / 64, 256, 0, stream>>>(
        h1, Wt2, h2, as2, ad2, alS, alD, N_NODES);
    gat_aggregate<<<N_NODES, 64, 0, stream>>>(h2, alS, alD, rstart, csr, b2, h0);

    // Pool + classify
    pool_partial<<<dim3(N_GRAPHS, 16), HID, 0, stream>>>(h0, gstart, pool);
    classify<<<N_GRAPHS, HID, 0, stream>>>(pool, gstart, Wc, bc, out);
}